// Round 1
// baseline (1178.320 us; speedup 1.0000x reference)
//
#include <hip/hip_runtime.h>
#include <hip/hip_bf16.h>
#include <math.h>

#define B 64
#define L 2048
#define C 1024          // D_K = D_Q
#define NH 8
#define DK 128
#define SCALE 0.08838834764831845f   // 1/sqrt(128)

// ---------------------------------------------------------------------------
// k_qs: qs[b, j] = bias[j] + sum_c q[b,c] * wq[j,c]        (64 x 1024)
// wave-per-4-rows, W rows in registers, loop over b (q is L2-resident).
__global__ void k_qs(const float* __restrict__ q, const float* __restrict__ wq,
                     const float* __restrict__ bq, float* __restrict__ qs) {
    int t = threadIdx.x, w = t >> 6, lane = t & 63;
    int j0 = blockIdx.x * 16 + w * 4;
    float4 W[4][4];
#pragma unroll
    for (int r = 0; r < 4; r++)
#pragma unroll
        for (int kk = 0; kk < 4; kk++)
            W[r][kk] = *(const float4*)&wq[(size_t)(j0 + r) * C + kk * 256 + lane * 4];
    for (int b = 0; b < B; b++) {
        float4 qv[4];
#pragma unroll
        for (int kk = 0; kk < 4; kk++)
            qv[kk] = *(const float4*)&q[(size_t)b * C + kk * 256 + lane * 4];
        float s[4] = {0.f, 0.f, 0.f, 0.f};
#pragma unroll
        for (int r = 0; r < 4; r++)
#pragma unroll
            for (int kk = 0; kk < 4; kk++)
                s[r] += W[r][kk].x * qv[kk].x + W[r][kk].y * qv[kk].y +
                        W[r][kk].z * qv[kk].z + W[r][kk].w * qv[kk].w;
#pragma unroll
        for (int r = 0; r < 4; r++) {
            float v = s[r];
#pragma unroll
            for (int off = 32; off; off >>= 1) v += __shfl_xor(v, off, 64);
            s[r] = v;
        }
        if (lane == 0) {
#pragma unroll
            for (int r = 0; r < 4; r++)
                qs[(size_t)b * C + j0 + r] = s[r] + bq[j0 + r];
        }
    }
}

// ---------------------------------------------------------------------------
// k_qtilde: qtilde[b,n,c] = SCALE * sum_d qs[b, n*128+d] * wk[n*128+d, c]
// grid (n=8, bgroup=8); 8 b's per block share the wk rows.
__global__ void k_qtilde(const float* __restrict__ qs, const float* __restrict__ wk,
                         float* __restrict__ qtilde) {
    int n = blockIdx.x, bg = blockIdx.y;
    int t = threadIdx.x;
    __shared__ float qss[8][128];
    for (int p = 0; p < 4; p++) {
        int e = p * 256 + t;
        int i = e >> 7, d = e & 127;
        qss[i][d] = qs[(size_t)(bg * 8 + i) * C + n * DK + d];
    }
    __syncthreads();
    float acc[8][4];
#pragma unroll
    for (int i = 0; i < 8; i++)
#pragma unroll
        for (int j = 0; j < 4; j++) acc[i][j] = 0.f;
    for (int d = 0; d < DK; d++) {
        float4 wv = *(const float4*)&wk[(size_t)(n * DK + d) * C + t * 4];
#pragma unroll
        for (int i = 0; i < 8; i++) {
            float s = qss[i][d];
            acc[i][0] += s * wv.x; acc[i][1] += s * wv.y;
            acc[i][2] += s * wv.z; acc[i][3] += s * wv.w;
        }
    }
#pragma unroll
    for (int i = 0; i < 8; i++) {
        float4 o = make_float4(acc[i][0] * SCALE, acc[i][1] * SCALE,
                               acc[i][2] * SCALE, acc[i][3] * SCALE);
        *(float4*)&qtilde[((size_t)(bg * 8 + i) * NH + n) * C + t * 4] = o;
    }
}

// ---------------------------------------------------------------------------
// k_scores: scores[n,b,l] = qtilde[b,n,:] . k[b,l,:]   (written to d_out attn region)
// grid (32 l-tiles, 64 b); qtilde[b] staged in LDS (32KB); wave does 2 rows at a time.
__global__ void k_scores(const float* __restrict__ kmat, const float* __restrict__ qtilde,
                         float* __restrict__ scores) {
    int lt = blockIdx.x, b = blockIdx.y;
    int t = threadIdx.x, w = t >> 6, lane = t & 63;
    __shared__ __align__(16) float qt[NH * C];
    for (int p = 0; p < 8; p++) {
        int i4 = p * 256 + t;
        *(float4*)&qt[i4 * 4] = *(const float4*)&qtilde[(size_t)b * NH * C + i4 * 4];
    }
    __syncthreads();
    const float* kb = kmat + (size_t)b * L * C;
    for (int rr = 0; rr < 16; rr += 2) {
        int l0 = lt * 64 + w * 16 + rr;
        const float* kr0 = kb + (size_t)l0 * C;
        const float* kr1 = kr0 + C;
        float4 kv0[4], kv1[4];
#pragma unroll
        for (int kk = 0; kk < 4; kk++) {
            kv0[kk] = *(const float4*)&kr0[kk * 256 + lane * 4];
            kv1[kk] = *(const float4*)&kr1[kk * 256 + lane * 4];
        }
        float a0[8], a1[8];
#pragma unroll
        for (int n = 0; n < 8; n++) { a0[n] = 0.f; a1[n] = 0.f; }
#pragma unroll
        for (int kk = 0; kk < 4; kk++) {
#pragma unroll
            for (int n = 0; n < 8; n++) {
                float4 qv = *(const float4*)&qt[n * C + kk * 256 + lane * 4];
                a0[n] += qv.x * kv0[kk].x + qv.y * kv0[kk].y + qv.z * kv0[kk].z + qv.w * kv0[kk].w;
                a1[n] += qv.x * kv1[kk].x + qv.y * kv1[kk].y + qv.z * kv1[kk].z + qv.w * kv1[kk].w;
            }
        }
#pragma unroll
        for (int n = 0; n < 8; n++) {
            float s0 = a0[n], s1 = a1[n];
#pragma unroll
            for (int off = 32; off; off >>= 1) {
                s0 += __shfl_xor(s0, off, 64);
                s1 += __shfl_xor(s1, off, 64);
            }
            a0[n] = s0; a1[n] = s1;
        }
        if (lane == 0) {
#pragma unroll
            for (int n = 0; n < 8; n++) {
                scores[(size_t)n * B * L + (size_t)b * L + l0]     = a0[n];
                scores[(size_t)n * B * L + (size_t)b * L + l0 + 1] = a1[n];
            }
        }
    }
}

// ---------------------------------------------------------------------------
// k_softmax: in-place row softmax over l for each (n,b) row, with mask.
__global__ void k_softmax(float* __restrict__ attn, const unsigned char* __restrict__ mask) {
    int row = blockIdx.x;            // row = n*64 + b
    int b = row & 63;
    float* p = attn + (size_t)row * L;
    const unsigned char* mrow = mask + (size_t)b * L;
    int t = threadIdx.x, w = t >> 6, lane = t & 63;
    __shared__ float red[8];
    float v[8];
    float mx = -INFINITY;
#pragma unroll
    for (int j = 0; j < 8; j++) {
        int pos = j * 256 + t;
        float x = p[pos];
        if (mrow[pos]) x = -INFINITY;
        v[j] = x;
        mx = fmaxf(mx, x);
    }
#pragma unroll
    for (int off = 32; off; off >>= 1) mx = fmaxf(mx, __shfl_xor(mx, off, 64));
    if (lane == 0) red[w] = mx;
    __syncthreads();
    mx = fmaxf(fmaxf(red[0], red[1]), fmaxf(red[2], red[3]));
    float s = 0.f;
#pragma unroll
    for (int j = 0; j < 8; j++) {
        v[j] = __expf(v[j] - mx);
        s += v[j];
    }
#pragma unroll
    for (int off = 32; off; off >>= 1) s += __shfl_xor(s, off, 64);
    if (lane == 0) red[4 + w] = s;
    __syncthreads();
    s = red[4] + red[5] + red[6] + red[7];
    float inv = 1.0f / s;
#pragma unroll
    for (int j = 0; j < 8; j++) p[j * 256 + t] = v[j] * inv;
}

// ---------------------------------------------------------------------------
// k_ctx: ctxpart[lp][b][n][c] = sum_{l in quarter} attn[n,b,l] * k[b,l,c]
// grid (b=64, lp=4); thread owns a float4 of c; attn chunk broadcast from LDS.
__global__ void k_ctx(const float* __restrict__ kmat, const float* __restrict__ attn,
                      float* __restrict__ ctxpart) {
    int b = blockIdx.x, lp = blockIdx.y;
    int t = threadIdx.x;
    __shared__ __align__(16) float at[NH][128];
    float acc[8][4];
#pragma unroll
    for (int n = 0; n < 8; n++)
#pragma unroll
        for (int j = 0; j < 4; j++) acc[n][j] = 0.f;
    const float* kb = kmat + (size_t)b * L * C;
    for (int sub = 0; sub < 4; sub++) {
        int l0 = lp * 512 + sub * 128;
        __syncthreads();
        for (int p = 0; p < 4; p++) {
            int e = p * 256 + t;
            int n = e >> 7, li = e & 127;
            at[n][li] = attn[((size_t)n * B + b) * L + l0 + li];
        }
        __syncthreads();
        for (int lq = 0; lq < 32; lq++) {
            int l = l0 + lq * 4;
            float4 kv0 = *(const float4*)&kb[(size_t)l * C + t * 4];
            float4 kv1 = *(const float4*)&kb[(size_t)(l + 1) * C + t * 4];
            float4 kv2 = *(const float4*)&kb[(size_t)(l + 2) * C + t * 4];
            float4 kv3 = *(const float4*)&kb[(size_t)(l + 3) * C + t * 4];
#pragma unroll
            for (int n = 0; n < 8; n++) {
                float4 a = *(const float4*)&at[n][lq * 4];
                acc[n][0] += a.x * kv0.x + a.y * kv1.x + a.z * kv2.x + a.w * kv3.x;
                acc[n][1] += a.x * kv0.y + a.y * kv1.y + a.z * kv2.y + a.w * kv3.y;
                acc[n][2] += a.x * kv0.z + a.y * kv1.z + a.z * kv2.z + a.w * kv3.z;
                acc[n][3] += a.x * kv0.w + a.y * kv1.w + a.z * kv2.w + a.w * kv3.w;
            }
        }
    }
#pragma unroll
    for (int n = 0; n < 8; n++) {
        float4 o = make_float4(acc[n][0], acc[n][1], acc[n][2], acc[n][3]);
        *(float4*)&ctxpart[(((size_t)lp * B + b) * NH + n) * C + t * 4] = o;
    }
}

// ---------------------------------------------------------------------------
// k_ctxsum: ctxsum = sum of 4 partials (written over qtilde slot).
__global__ void k_ctxsum(const float* __restrict__ part, float* __restrict__ ctxsum) {
    int idx = blockIdx.x * 256 + threadIdx.x;   // 131072 float4s
    const float4* p0 = (const float4*)part;
    const float4* p1 = p0 + B * NH * C / 4;
    const float4* p2 = p1 + B * NH * C / 4;
    const float4* p3 = p2 + B * NH * C / 4;
    float4 a = p0[idx], b = p1[idx], c = p2[idx], d = p3[idx];
    float4 o = make_float4(a.x + b.x + c.x + d.x, a.y + b.y + c.y + d.y,
                           a.z + b.z + c.z + d.z, a.w + b.w + c.w + d.w);
    ((float4*)ctxsum)[idx] = o;
}

// ---------------------------------------------------------------------------
// k_out: output[b, j] = bv[j] + sum_c wv[j,c] * ctxsum[b, n(j), c]
__global__ void k_out(const float* __restrict__ ctxsum, const float* __restrict__ wv,
                      const float* __restrict__ bv, float* __restrict__ out) {
    int t = threadIdx.x, w = t >> 6, lane = t & 63;
    int j0 = blockIdx.x * 16 + w * 4;
    int n = j0 >> 7;
    float4 W[4][4];
#pragma unroll
    for (int r = 0; r < 4; r++)
#pragma unroll
        for (int kk = 0; kk < 4; kk++)
            W[r][kk] = *(const float4*)&wv[(size_t)(j0 + r) * C + kk * 256 + lane * 4];
    for (int b = 0; b < B; b++) {
        float4 cv[4];
#pragma unroll
        for (int kk = 0; kk < 4; kk++)
            cv[kk] = *(const float4*)&ctxsum[((size_t)b * NH + n) * C + kk * 256 + lane * 4];
        float s[4] = {0.f, 0.f, 0.f, 0.f};
#pragma unroll
        for (int r = 0; r < 4; r++)
#pragma unroll
            for (int kk = 0; kk < 4; kk++)
                s[r] += W[r][kk].x * cv[kk].x + W[r][kk].y * cv[kk].y +
                        W[r][kk].z * cv[kk].z + W[r][kk].w * cv[kk].w;
#pragma unroll
        for (int r = 0; r < 4; r++) {
            float v = s[r];
#pragma unroll
            for (int off = 32; off; off >>= 1) v += __shfl_xor(v, off, 64);
            s[r] = v;
        }
        if (lane == 0) {
#pragma unroll
            for (int r = 0; r < 4; r++)
                out[(size_t)b * (NH * DK) + j0 + r] = s[r] + bv[j0 + r];
        }
    }
}

// ---------------------------------------------------------------------------
extern "C" void kernel_launch(void* const* d_in, const int* in_sizes, int n_in,
                              void* d_out, int out_size, void* d_ws, size_t ws_size,
                              hipStream_t stream) {
    const float* q    = (const float*)d_in[0];
    const float* kmat = (const float*)d_in[1];
    const unsigned char* mask = (const unsigned char*)d_in[2];
    const float* wq = (const float*)d_in[3];
    const float* bq = (const float*)d_in[4];
    const float* wk = (const float*)d_in[5];
    // d_in[6] = w_ks_b: softmax-invariant (constant shift per (b,n) row) -> unused.
    const float* wv = (const float*)d_in[7];
    const float* bv = (const float*)d_in[8];

    float* out  = (float*)d_out;            // (64, 1024)
    float* attn = out + B * NH * DK;        // (8*64, 2048)  == scores buffer

    float* ws      = (float*)d_ws;
    float* qs      = ws;                     // 65536 floats
    float* qtilde  = ws + 65536;             // 524288 floats (reused as ctxsum)
    float* ctxpart = ws + 65536 + 524288;    // 4 * 524288 floats

    hipLaunchKernelGGL(k_qs, dim3(64), dim3(256), 0, stream, q, wq, bq, qs);
    hipLaunchKernelGGL(k_qtilde, dim3(8, 8), dim3(256), 0, stream, qs, wk, qtilde);
    hipLaunchKernelGGL(k_scores, dim3(32, 64), dim3(256), 0, stream, kmat, qtilde, attn);
    hipLaunchKernelGGL(k_softmax, dim3(512), dim3(256), 0, stream, attn, mask);
    hipLaunchKernelGGL(k_ctx, dim3(64, 4), dim3(256), 0, stream, kmat, attn, ctxpart);
    hipLaunchKernelGGL(k_ctxsum, dim3(512), dim3(256), 0, stream, ctxpart, qtilde);
    hipLaunchKernelGGL(k_out, dim3(64), dim3(256), 0, stream, qtilde, wv, bv, out);
}

// Round 2
// 523.945 us; speedup vs baseline: 2.2489x; 2.2489x over previous
//
#include <hip/hip_runtime.h>
#include <hip/hip_bf16.h>
#include <math.h>

#define B 64
#define L 2048
#define C 1024          // D_K = D_Q
#define NH 8
#define DK 128
#define SCALE 0.08838834764831845f   // 1/sqrt(128)

// ---------------------------------------------------------------------------
// k_qs: qs[b, j] = bias[j] + sum_c q[b,c] * wq[j,c]        (64 x 1024)
__global__ void k_qs(const float* __restrict__ q, const float* __restrict__ wq,
                     const float* __restrict__ bq, float* __restrict__ qs) {
    int t = threadIdx.x, w = t >> 6, lane = t & 63;
    int j0 = blockIdx.x * 16 + w * 4;
    float4 W[4][4];
#pragma unroll
    for (int r = 0; r < 4; r++)
#pragma unroll
        for (int kk = 0; kk < 4; kk++)
            W[r][kk] = *(const float4*)&wq[(size_t)(j0 + r) * C + kk * 256 + lane * 4];
    for (int b = 0; b < B; b++) {
        float4 qv[4];
#pragma unroll
        for (int kk = 0; kk < 4; kk++)
            qv[kk] = *(const float4*)&q[(size_t)b * C + kk * 256 + lane * 4];
        float s[4] = {0.f, 0.f, 0.f, 0.f};
#pragma unroll
        for (int r = 0; r < 4; r++)
#pragma unroll
            for (int kk = 0; kk < 4; kk++)
                s[r] += W[r][kk].x * qv[kk].x + W[r][kk].y * qv[kk].y +
                        W[r][kk].z * qv[kk].z + W[r][kk].w * qv[kk].w;
#pragma unroll
        for (int r = 0; r < 4; r++) {
            float v = s[r];
#pragma unroll
            for (int off = 32; off; off >>= 1) v += __shfl_xor(v, off, 64);
            s[r] = v;
        }
        if (lane == 0) {
#pragma unroll
            for (int r = 0; r < 4; r++)
                qs[(size_t)b * C + j0 + r] = s[r] + bq[j0 + r];
        }
    }
}

// ---------------------------------------------------------------------------
// k_qtilde: qtilde[b,n,c] = SCALE * sum_d qs[b, n*128+d] * wk[n*128+d, c]
__global__ void k_qtilde(const float* __restrict__ qs, const float* __restrict__ wk,
                         float* __restrict__ qtilde) {
    int n = blockIdx.x, bg = blockIdx.y;
    int t = threadIdx.x;
    __shared__ float qss[8][128];
    for (int p = 0; p < 4; p++) {
        int e = p * 256 + t;
        int i = e >> 7, d = e & 127;
        qss[i][d] = qs[(size_t)(bg * 8 + i) * C + n * DK + d];
    }
    __syncthreads();
    float acc[8][4];
#pragma unroll
    for (int i = 0; i < 8; i++)
#pragma unroll
        for (int j = 0; j < 4; j++) acc[i][j] = 0.f;
    for (int d = 0; d < DK; d++) {
        float4 wv = *(const float4*)&wk[(size_t)(n * DK + d) * C + t * 4];
#pragma unroll
        for (int i = 0; i < 8; i++) {
            float s = qss[i][d];
            acc[i][0] += s * wv.x; acc[i][1] += s * wv.y;
            acc[i][2] += s * wv.z; acc[i][3] += s * wv.w;
        }
    }
#pragma unroll
    for (int i = 0; i < 8; i++) {
        float4 o = make_float4(acc[i][0] * SCALE, acc[i][1] * SCALE,
                               acc[i][2] * SCALE, acc[i][3] * SCALE);
        *(float4*)&qtilde[((size_t)(bg * 8 + i) * NH + n) * C + t * 4] = o;
    }
}

// ---------------------------------------------------------------------------
// k_fused: single pass over k. For each (b, l-quarter):
//   scores (raw, written to attn buffer) + online softmax + ctx partial accum.
// thread owns float2 of c; block = 512 threads, 512 rows, 4 rows/iter.
__global__ __launch_bounds__(512, 1) void k_fused(
    const float* __restrict__ kmat, const float* __restrict__ qtilde,
    const unsigned char* __restrict__ mask,
    float* __restrict__ rawsc,            // (n*B + b)*L + l
    float* __restrict__ accpart,          // [b][lp][n][C]
    float* __restrict__ mzpart) {         // [b][lp][n] float2 {m, Z}
    const int b = blockIdx.x, lp = blockIdx.y;
    const int t = threadIdx.x;
    const int l_base = lp * 512;
    __shared__ float sred[512][33];
    __shared__ __align__(16) float sfin[32];

    float2 qt2[NH];
#pragma unroll
    for (int n = 0; n < NH; n++)
        qt2[n] = *(const float2*)&qtilde[((size_t)b * NH + n) * C + t * 2];

    float mrun[NH], zrun[NH];
    float2 acc[NH];
#pragma unroll
    for (int n = 0; n < NH; n++) {
        mrun[n] = -INFINITY; zrun[n] = 0.f; acc[n] = make_float2(0.f, 0.f);
    }

    const float* kb = kmat + (size_t)b * L * C;

    float2 kvA[4], kvB[4];
    auto LOADK = [&](float2 (&kv)[4], int it) {
#pragma unroll
        for (int r = 0; r < 4; r++) {
            int l = l_base + it * 4 + r;
            if (l > L - 1) l = L - 1;                 // clamp (prefetch overrun)
            kv[r] = *(const float2*)&kb[(size_t)l * C + t * 2];
        }
    };
    auto STEP = [&](float2 (&kv)[4], int it) {
        int l0 = l_base + it * 4;
        // partial dots -> LDS
#pragma unroll
        for (int r = 0; r < 4; r++)
#pragma unroll
            for (int n = 0; n < NH; n++)
                sred[t][r * 8 + n] = kv[r].x * qt2[n].x + kv[r].y * qt2[n].y;
        __syncthreads();
        // transpose-reduce: 32 groups x 16 threads; rotated rows (bank-friendly)
        int g = t >> 4, sub = t & 15;
        float psum = 0.f;
#pragma unroll
        for (int m = 0; m < 32; m++) {
            int row = sub * 32 + ((m + sub * 2) & 31);
            psum += sred[row][g];
        }
#pragma unroll
        for (int off = 8; off; off >>= 1) psum += __shfl_xor(psum, off, 64);
        if (sub == 0) sfin[g] = psum;
        __syncthreads();
        // coalesced raw-score store (8 threads, float4 over r)
        if (t < 8) {
            float4 o = make_float4(sfin[t], sfin[8 + t], sfin[16 + t], sfin[24 + t]);
            *(float4*)&rawsc[((size_t)t * B + b) * L + l0] = o;
        }
        // broadcast all 32 sums
        float sv[32];
#pragma unroll
        for (int q = 0; q < 8; q++) {
            float4 f = *(const float4*)&sfin[q * 4];
            sv[q * 4 + 0] = f.x; sv[q * 4 + 1] = f.y;
            sv[q * 4 + 2] = f.z; sv[q * 4 + 3] = f.w;
        }
        // mask (additive -inf), block-uniform
        uchar4 mb = *(const uchar4*)&mask[(size_t)b * L + l0];
        float madd0 = mb.x ? -INFINITY : 0.f;
        float madd1 = mb.y ? -INFINITY : 0.f;
        float madd2 = mb.z ? -INFINITY : 0.f;
        float madd3 = mb.w ? -INFINITY : 0.f;
        // online softmax + ctx accumulate
#pragma unroll
        for (int n = 0; n < NH; n++) {
            float s0 = sv[n] + madd0, s1 = sv[8 + n] + madd1;
            float s2 = sv[16 + n] + madd2, s3 = sv[24 + n] + madd3;
            float mx = fmaxf(fmaxf(s0, s1), fmaxf(s2, s3));
            float mnew = fmaxf(mrun[n], mx);
            float e;
            if (mnew == -INFINITY) e = 1.0f;
            else if (mrun[n] == -INFINITY) e = 0.0f;
            else e = __expf(mrun[n] - mnew);
            float p0 = (s0 == -INFINITY) ? 0.f : __expf(s0 - mnew);
            float p1 = (s1 == -INFINITY) ? 0.f : __expf(s1 - mnew);
            float p2 = (s2 == -INFINITY) ? 0.f : __expf(s2 - mnew);
            float p3 = (s3 == -INFINITY) ? 0.f : __expf(s3 - mnew);
            zrun[n] = zrun[n] * e + (p0 + p1) + (p2 + p3);
            acc[n].x = acc[n].x * e + p0 * kv[0].x + p1 * kv[1].x + p2 * kv[2].x + p3 * kv[3].x;
            acc[n].y = acc[n].y * e + p0 * kv[0].y + p1 * kv[1].y + p2 * kv[2].y + p3 * kv[3].y;
            mrun[n] = mnew;
        }
    };

    LOADK(kvA, 0);
    for (int it = 0; it < 128; it += 2) {
        LOADK(kvB, it + 1);
        STEP(kvA, it);
        LOADK(kvA, it + 2);   // clamped when it+2 == 128
        STEP(kvB, it + 1);
    }

    // epilogue: write partials
    float* ap = accpart + (((size_t)b * 4 + lp) * NH) * C;
#pragma unroll
    for (int n = 0; n < NH; n++)
        *(float2*)&ap[(size_t)n * C + t * 2] = acc[n];
    if (t == 0) {
        float2* mz = (float2*)mzpart;
#pragma unroll
        for (int n = 0; n < NH; n++)
            mz[((size_t)b * 4 + lp) * NH + n] = make_float2(mrun[n], zrun[n]);
    }
}

// ---------------------------------------------------------------------------
// k_combine: merge the 4 l-quarter partials per b -> ctx, Mfin, Zinv.
__global__ void k_combine(const float* __restrict__ accpart, const float* __restrict__ mzpart,
                          float* __restrict__ ctx, float* __restrict__ Mfin,
                          float* __restrict__ Zinv) {
    int b = blockIdx.x, t = threadIdx.x;
    __shared__ float2 mzs[4][8];
    if (t < 32) mzs[t >> 3][t & 7] = ((const float2*)mzpart)[((size_t)b * 4 + (t >> 3)) * NH + (t & 7)];
    __syncthreads();
    float E[4][8], Zi[8], M[8];
#pragma unroll
    for (int n = 0; n < 8; n++) {
        float m0 = mzs[0][n].x, m1 = mzs[1][n].x, m2 = mzs[2][n].x, m3 = mzs[3][n].x;
        float Mn = fmaxf(fmaxf(m0, m1), fmaxf(m2, m3));
        float Zg = 0.f;
#pragma unroll
        for (int lp = 0; lp < 4; lp++) {
            float ml = mzs[lp][n].x, zl = mzs[lp][n].y;
            float e = (ml == -INFINITY) ? 0.f : __expf(ml - Mn);
            E[lp][n] = e;
            Zg += zl * e;
        }
        M[n] = Mn; Zi[n] = 1.0f / Zg;
    }
    const float* ap = accpart + ((size_t)b * 4) * NH * C;
#pragma unroll
    for (int n = 0; n < 8; n++) {
        float4 s = make_float4(0.f, 0.f, 0.f, 0.f);
#pragma unroll
        for (int lp = 0; lp < 4; lp++) {
            float4 a = *(const float4*)&ap[((size_t)lp * NH + n) * C + t * 4];
            float e = E[lp][n];
            s.x += a.x * e; s.y += a.y * e; s.z += a.z * e; s.w += a.w * e;
        }
        float zi = Zi[n];
        s.x *= zi; s.y *= zi; s.z *= zi; s.w *= zi;
        *(float4*)&ctx[((size_t)b * NH + n) * C + t * 4] = s;
    }
    if (t == 0) {
#pragma unroll
        for (int n = 0; n < 8; n++) { Mfin[n * B + b] = M[n]; Zinv[n * B + b] = Zi[n]; }
    }
}

// ---------------------------------------------------------------------------
// k_attnnorm: attn[row, l] = mask ? 0 : exp(raw - M) * Zinv, in place.
__global__ void k_attnnorm(float* __restrict__ attn, const unsigned char* __restrict__ mask,
                           const float* __restrict__ Mfin, const float* __restrict__ Zinv) {
    int row = blockIdx.x;            // n*64 + b
    int b = row & 63;
    int t = threadIdx.x;
    float M = Mfin[row], Zi = Zinv[row];
    float* p = attn + (size_t)row * L;
    const unsigned char* mr = mask + (size_t)b * L;
#pragma unroll
    for (int j = 0; j < 2; j++) {
        int pos = j * 1024 + t * 4;
        float4 s = *(const float4*)&p[pos];
        uchar4 mv = *(const uchar4*)&mr[pos];
        float4 o;
        o.x = mv.x ? 0.f : __expf(s.x - M) * Zi;
        o.y = mv.y ? 0.f : __expf(s.y - M) * Zi;
        o.z = mv.z ? 0.f : __expf(s.z - M) * Zi;
        o.w = mv.w ? 0.f : __expf(s.w - M) * Zi;
        *(float4*)&p[pos] = o;
    }
}

// ---------------------------------------------------------------------------
// k_out: output[b, j] = bv[j] + sum_c wv[j,c] * ctx[b, n(j), c]
__global__ void k_out(const float* __restrict__ ctxsum, const float* __restrict__ wv,
                      const float* __restrict__ bv, float* __restrict__ out) {
    int t = threadIdx.x, w = t >> 6, lane = t & 63;
    int j0 = blockIdx.x * 16 + w * 4;
    int n = j0 >> 7;
    float4 W[4][4];
#pragma unroll
    for (int r = 0; r < 4; r++)
#pragma unroll
        for (int kk = 0; kk < 4; kk++)
            W[r][kk] = *(const float4*)&wv[(size_t)(j0 + r) * C + kk * 256 + lane * 4];
    for (int b = 0; b < B; b++) {
        float4 cv[4];
#pragma unroll
        for (int kk = 0; kk < 4; kk++)
            cv[kk] = *(const float4*)&ctxsum[((size_t)b * NH + n) * C + kk * 256 + lane * 4];
        float s[4] = {0.f, 0.f, 0.f, 0.f};
#pragma unroll
        for (int r = 0; r < 4; r++)
#pragma unroll
            for (int kk = 0; kk < 4; kk++)
                s[r] += W[r][kk].x * cv[kk].x + W[r][kk].y * cv[kk].y +
                        W[r][kk].z * cv[kk].z + W[r][kk].w * cv[kk].w;
#pragma unroll
        for (int r = 0; r < 4; r++) {
            float v = s[r];
#pragma unroll
            for (int off = 32; off; off >>= 1) v += __shfl_xor(v, off, 64);
            s[r] = v;
        }
        if (lane == 0) {
#pragma unroll
            for (int r = 0; r < 4; r++)
                out[(size_t)b * (NH * DK) + j0 + r] = s[r] + bv[j0 + r];
        }
    }
}

// ---------------------------------------------------------------------------
extern "C" void kernel_launch(void* const* d_in, const int* in_sizes, int n_in,
                              void* d_out, int out_size, void* d_ws, size_t ws_size,
                              hipStream_t stream) {
    const float* q    = (const float*)d_in[0];
    const float* kmat = (const float*)d_in[1];
    const unsigned char* mask = (const unsigned char*)d_in[2];
    const float* wq = (const float*)d_in[3];
    const float* bq = (const float*)d_in[4];
    const float* wk = (const float*)d_in[5];
    // d_in[6] = w_ks_b: softmax-invariant -> unused.
    const float* wv = (const float*)d_in[7];
    const float* bv = (const float*)d_in[8];

    float* out  = (float*)d_out;            // (64, 1024)
    float* attn = out + B * NH * DK;        // (8*64, 2048) raw scores -> softmax

    float* ws      = (float*)d_ws;
    // region 0 (65536 floats): qs, dead after k_qtilde; then overlaid:
    float* qs      = ws;
    float* mzpart  = ws;                     // 4096 floats (64*4*8*2)
    float* Mfin    = ws + 4096;              // 512
    float* Zinv    = ws + 4608;              // 512
    // region 1: qtilde (524288 floats), reused as ctx by k_combine
    float* qtilde  = ws + 65536;
    float* ctx     = qtilde;
    // region 2: accpart (64*4*8*1024 = 2097152 floats)
    float* accpart = ws + 65536 + 524288;

    hipLaunchKernelGGL(k_qs, dim3(64), dim3(256), 0, stream, q, wq, bq, qs);
    hipLaunchKernelGGL(k_qtilde, dim3(8, 8), dim3(256), 0, stream, qs, wk, qtilde);
    hipLaunchKernelGGL(k_fused, dim3(64, 4), dim3(512), 0, stream,
                       kmat, qtilde, mask, attn, accpart, mzpart);
    hipLaunchKernelGGL(k_combine, dim3(64), dim3(256), 0, stream,
                       accpart, mzpart, ctx, Mfin, Zinv);
    hipLaunchKernelGGL(k_attnnorm, dim3(512), dim3(256), 0, stream, attn, mask, Mfin, Zinv);
    hipLaunchKernelGGL(k_out, dim3(64), dim3(256), 0, stream, ctx, wv, bv, out);
}